// Round 1
// baseline (37107.428 us; speedup 1.0000x reference)
//
#include <hip/hip_runtime.h>
#include <hip/hip_fp16.h>

static constexpr int kH   = 2048;
static constexpr int kS   = 8192;
static constexpr int kNWG = 256;
static constexpr int kTHR = 512;

typedef float        v2f __attribute__((ext_vector_type(2)));
typedef unsigned int v4u __attribute__((ext_vector_type(4)));

__device__ __forceinline__ v2f unpk_bf(unsigned int u) {
    union { unsigned int i; float f; } lo, hi;
    lo.i = u << 16; hi.i = u & 0xffff0000u;
    v2f r; r[0] = lo.f; r[1] = hi.f; return r;
}
__device__ __forceinline__ unsigned int pkbf(float lo, float hi) {
    union { float f; unsigned int u; } a, b; a.f = lo; b.f = hi;
    unsigned int ar = a.u + 0x7fffu + ((a.u >> 16) & 1u);
    unsigned int br = b.u + 0x7fffu + ((b.u >> 16) & 1u);
    return (ar >> 16) | (br & 0xffff0000u);
}
__device__ __forceinline__ v2f cvt2h(unsigned int u) {
    __half2 h = *(__half2*)&u;
    float2 f = __half22float2(h);
    v2f r; r[0] = f.x; r[1] = f.y; return r;
}

// MALL-coherent poll: 4 x dwordx4, 1 KB lane-stride apart, single drain.
__device__ __forceinline__ void poll4(const void* p, v4u& a, v4u& b, v4u& c, v4u& d) {
    asm volatile("global_load_dwordx4 %0, %4, off sc0 sc1\n\t"
                 "global_load_dwordx4 %1, %4, off offset:1024 sc0 sc1\n\t"
                 "global_load_dwordx4 %2, %4, off offset:2048 sc0 sc1\n\t"
                 "global_load_dwordx4 %3, %4, off offset:3072 sc0 sc1\n\t"
                 "s_waitcnt vmcnt(0)"
                 : "=&v"(a), "=&v"(b), "=&v"(c), "=&v"(d) : "v"(p) : "memory");
}
// Single 16B coherent store: h[8] as f16 + embedded toggle bit (one packet).
__device__ __forceinline__ void store16_coh(void* p, v4u v) {
    asm volatile("global_store_dwordx4 %0, %1, off sc0 sc1"
                 :: "v"(p), "v"(v) : "memory");
}

// Persistent GRU. 256 WGs x 512 threads (8 waves), one WG per CU.
// Wave wv owns element e = wg*8+wv; lane l covers cols c = 4l + 256m + k.
// Publish protocol: WG's h[8] as f16 = ONE dwordx4 record; toggle bit
// toggle(s) = ((s>>1)^s)&1 embedded in record LSB; 2 slots (s&1) kill ABA.
// Detect loads ARE the data: zero separate gather, zero drain, zero flag.
//
// This revision strips three serializers off the publish->detect path:
//  (1) x[t+1] row is prefetched into registers during h-proj/reduce (the
//      publish->poll gap no longer eats the L2 latency of 8 float4 loads);
//  (2) the publisher is wave 1 (tid==64), so wave 0's poll4 vmcnt(0) never
//      waits on our own write-through store;
//  (3) the second __syncthreads (whose implicit vmcnt(0) drain would also
//      kill (1)) is replaced by a tag-in-dword LDS handshake: lane 0 of
//      each wave writes f16(h)|((t+1)<<16) into hpubd[wv]; the publisher
//      spins on the 8 dwords (tag+payload atomic in one word) and fires
//      the coherent store the moment the last reduce lands.
__global__ __launch_bounds__(kTHR, 2)
void gru_persistent(const float* __restrict__ x,    // [S,H] f32
                    const float* __restrict__ Wih,  // [3H,H] f32
                    const float* __restrict__ Whh,  // [3H,H] f32
                    const float* __restrict__ bih,  // [3H] f32
                    const float* __restrict__ bhh,  // [3H] f32
                    float* __restrict__ out,        // [H] f32
                    unsigned char* __restrict__ rec) // 2 slots * 4096 B (zeroed)
{
    __shared__ __align__(16) unsigned short hlds[kH];   // h_t as f16, col c at [c]
    __shared__ __align__(16) unsigned int   hpubd[8];   // f16 | ((t+1)<<16)

    const int wg  = blockIdx.x;
    const int tid = threadIdx.x;
    const int wv  = tid >> 6;      // 0..7
    const int l   = tid & 63;      // 0..63
    const int e   = wg * 8 + wv;
    const int cb  = 4 * l;         // cols cb + 256m + k, m<8, k<4

    if (tid < 8) hpubd[tid] = 0u;  // no stale-tag false trigger at t=0
                                   // (ordered before first reader by sync1 of t=0)

    // Weights: W_hh slice as f32 pairs (96 regs), W_ih as packed bf16 (48).
    v2f   whh2[3][8][2];
    uint2 wihp[3][8];
#pragma unroll
    for (int G = 0; G < 3; ++G) {
        const size_t row = (size_t)(G * kH + e) * kH;
#pragma unroll
        for (int m = 0; m < 8; ++m) {
            const size_t off = row + cb + 256 * m;
            const float4 w = *(const float4*)(Whh + off);
            whh2[G][m][0][0] = w.x; whh2[G][m][0][1] = w.y;
            whh2[G][m][1][0] = w.z; whh2[G][m][1][1] = w.w;
            const float4 iw = *(const float4*)(Wih + off);
            wihp[G][m].x = pkbf(iw.x, iw.y);
            wihp[G][m].y = pkbf(iw.z, iw.w);
        }
    }
    const float bir  = bih[e];
    const float biz  = bih[kH + e];
    const float bin_ = bih[2 * kH + e];
    const float bhr  = bhh[e];
    const float bhz  = bhh[kH + e];
    const float bhn  = bhh[2 * kH + e];

    float hold = 0.0f;  // h for element e (valid on l==0)

    // Prologue: x row 0 into registers.
    float4 xv[8];
#pragma unroll
    for (int m = 0; m < 8; ++m)
        xv[m] = *(const float4*)(x + cb + 256 * m);

#pragma unroll 1
    for (int t = 0; t < kS; ++t) {
        // ---- x projection from prefetched registers (fills publish->poll gap
        //      with pure VALU; no L2 latency before the poll starts) ----
        v2f ar = {0.f, 0.f}, az = {0.f, 0.f}, an = {0.f, 0.f};
#pragma unroll
        for (int m = 0; m < 8; ++m) {
            const float4 xvv = xv[m];
            v2f x0; x0[0] = xvv.x; x0[1] = xvv.y;
            v2f x1; x1[0] = xvv.z; x1[1] = xvv.w;
            ar += unpk_bf(wihp[0][m].x) * x0 + unpk_bf(wihp[0][m].y) * x1;
            az += unpk_bf(wihp[1][m].x) * x0 + unpk_bf(wihp[1][m].y) * x1;
            an += unpk_bf(wihp[2][m].x) * x0 + unpk_bf(wihp[2][m].y) * x1;
        }

        // ---- wave 0: poll all 256 records for step-t toggle; data = payload ----
        if (tid < 64) {
            const unsigned int tg = (unsigned int)(((t >> 1) ^ t) & 1);
            const char* base = (const char*)rec + (t & 1) * 4096 + tid * 16;
            v4u r0, r1, r2, r3;
            for (;;) {
                poll4(base, r0, r1, r2, r3);
                const int ok = ((r0.x & 1u) == tg) & ((r1.x & 1u) == tg) &
                               ((r2.x & 1u) == tg) & ((r3.x & 1u) == tg);
                if (__all(ok)) break;
            }
            // broadcast h_t to LDS: lane i writes records i, i+64, i+128, i+192
            *(v4u*)&hlds[tid * 8]         = r0;
            *(v4u*)&hlds[(tid + 64) * 8]  = r1;
            *(v4u*)&hlds[(tid + 128) * 8] = r2;
            *(v4u*)&hlds[(tid + 192) * 8] = r3;
        }
        __syncthreads();   // sync1: orders hlds broadcast vs h-proj reads

        // ---- prefetch x[t+1] (issued after sync1 so no barrier drains it;
        //      consumed at next loop top — flies under h-proj/reduce/publish) ----
        {
            const float* xnext = x + (size_t)(t + 1 < kS ? t + 1 : t) * kH;
#pragma unroll
            for (int m = 0; m < 8; ++m)
                xv[m] = *(const float4*)(xnext + cb + 256 * m);
        }

        // ---- h projection from LDS f16 (lane-contiguous b64 reads) ----
        v2f hr = {0.f, 0.f}, hz = {0.f, 0.f}, hn = {0.f, 0.f};
#pragma unroll
        for (int m = 0; m < 8; ++m) {
            const uint2 hu = *(const uint2*)&hlds[cb + 256 * m];
            const v2f h0 = cvt2h(hu.x);
            const v2f h1 = cvt2h(hu.y);
            hr += whh2[0][m][0] * h0 + whh2[0][m][1] * h1;
            hz += whh2[1][m][0] * h0 + whh2[1][m][1] * h1;
            hn += whh2[2][m][0] * h0 + whh2[2][m][1] * h1;
        }

        // ---- full-wave reduce (64 lanes -> lane 0 of each wave) ----
        float pr  = ar[0] + ar[1] + hr[0] + hr[1];
        float pz  = az[0] + az[1] + hz[0] + hz[1];
        float pxn = an[0] + an[1];
        float phn = hn[0] + hn[1];
#pragma unroll
        for (int m = 32; m >= 1; m >>= 1) {
            pr  += __shfl_xor(pr,  m, 64);
            pz  += __shfl_xor(pz,  m, 64);
            pxn += __shfl_xor(pxn, m, 64);
            phn += __shfl_xor(phn, m, 64);
        }

        if (l == 0) {
            const float r = 1.f / (1.f + __expf(-(pr + bir + bhr)));
            const float z = 1.f / (1.f + __expf(-(pz + biz + bhz)));
            const float a = (pxn + bin_) + r * (phn + bhn);
            const float ee = __expf(-2.f * fabsf(a));
            float th = (1.f - ee) / (1.f + ee);
            th = (a < 0.f) ? -th : th;
            hold = (1.f - z) * th + z * hold;
            const __half hh = __float2half(hold);
            const unsigned int hs = *(const unsigned short*)&hh;
            // tag + payload in ONE dword: cross-wave visibility is atomic,
            // no fence, no barrier needed.
            *(volatile unsigned int*)&hpubd[wv] =
                hs | (((unsigned int)(t + 1)) << 16);
        }

        // ---- publisher = wave 1 lane 0: spin on the 8 tagged dwords, then
        //      ONE 16B coherent store (data + toggle in one packet).
        //      Wave 0's poll counter stays clean of this store. ----
        if (tid == 64) {
            const unsigned int tagx = ((unsigned int)(t + 1)) << 16;
            volatile unsigned int* hp = hpubd;
            unsigned int d0, d1, d2, d3, d4, d5, d6, d7;
            for (;;) {
                d0 = hp[0]; d1 = hp[1]; d2 = hp[2]; d3 = hp[3];
                d4 = hp[4]; d5 = hp[5]; d6 = hp[6]; d7 = hp[7];
                const unsigned int mis =
                    (d0 ^ tagx) | (d1 ^ tagx) | (d2 ^ tagx) | (d3 ^ tagx) |
                    (d4 ^ tagx) | (d5 ^ tagx) | (d6 ^ tagx) | (d7 ^ tagx);
                if ((mis & 0xffff0000u) == 0u) break;
            }
            v4u p;
            p.x = (d0 & 0xffffu) | (d1 << 16);
            p.y = (d2 & 0xffffu) | (d3 << 16);
            p.z = (d4 & 0xffffu) | (d5 << 16);
            p.w = (d6 & 0xffffu) | (d7 << 16);
            const unsigned int tgw = (unsigned int)((((t + 1) >> 1) ^ (t + 1)) & 1);
            p.x = (p.x & ~1u) | tgw;
            store16_coh((char*)rec + ((t + 1) & 1) * 4096 + wg * 16, p);
        }
        // No second __syncthreads: hlds reuse is ordered transitively —
        // wave 0 re-broadcasts only after poll(t+1) succeeds, which requires
        // our record(t+1) stored, which requires all 8 hpubd writes, which
        // retire only after every wave's h-proj LDS reads of step t.
    }

    if (l == 0)
        out[e] = hold;
}

extern "C" void kernel_launch(void* const* d_in, const int* in_sizes, int n_in,
                              void* d_out, int out_size, void* d_ws, size_t ws_size,
                              hipStream_t stream) {
    (void)in_sizes; (void)n_in; (void)out_size; (void)ws_size;
    const float* x   = (const float*)d_in[0];
    const float* Wih = (const float*)d_in[1];
    const float* Whh = (const float*)d_in[2];
    const float* bih = (const float*)d_in[3];
    const float* bhh = (const float*)d_in[4];

    unsigned char* rec = (unsigned char*)d_ws;   // 2 slots * 4096 B
    hipMemsetAsync(rec, 0, 8192, stream);        // h_0 = 0, slot-0 toggle 0; slot-1 waits
    gru_persistent<<<dim3(kNWG), dim3(kTHR), 0, stream>>>(
        x, Wih, Whh, bih, bhh, (float*)d_out, rec);
}

// Round 4
// 18160.361 us; speedup vs baseline: 2.0433x; 2.0433x over previous
//
#include <hip/hip_runtime.h>
#include <hip/hip_fp16.h>

static constexpr int kH   = 2048;
static constexpr int kS   = 8192;
static constexpr int kNWG = 256;
static constexpr int kTHR = 512;

typedef float        v2f __attribute__((ext_vector_type(2)));
typedef unsigned int v4u __attribute__((ext_vector_type(4)));

__device__ __forceinline__ v2f unpk_bf(unsigned int u) {
    union { unsigned int i; float f; } lo, hi;
    lo.i = u << 16; hi.i = u & 0xffff0000u;
    v2f r; r[0] = lo.f; r[1] = hi.f; return r;
}
__device__ __forceinline__ unsigned int pkbf(float lo, float hi) {
    union { float f; unsigned int u; } a, b; a.f = lo; b.f = hi;
    unsigned int ar = a.u + 0x7fffu + ((a.u >> 16) & 1u);
    unsigned int br = b.u + 0x7fffu + ((b.u >> 16) & 1u);
    return (ar >> 16) | (br & 0xffff0000u);
}
__device__ __forceinline__ v2f cvt2h(unsigned int u) {
    __half2 h = *(__half2*)&u;
    float2 f = __half22float2(h);
    v2f r; r[0] = f.x; r[1] = f.y; return r;
}

// MALL-coherent poll: 4 x dwordx4, 1 KB lane-stride apart, single drain.
// (Blocking form — identical to the 21.8ms baseline; the pipelined variant
// samples memory at the same period, so it bought nothing and added risk.)
__device__ __forceinline__ void poll4(const void* p, v4u& a, v4u& b, v4u& c, v4u& d) {
    asm volatile("global_load_dwordx4 %0, %4, off sc0 sc1\n\t"
                 "global_load_dwordx4 %1, %4, off offset:1024 sc0 sc1\n\t"
                 "global_load_dwordx4 %2, %4, off offset:2048 sc0 sc1\n\t"
                 "global_load_dwordx4 %3, %4, off offset:3072 sc0 sc1\n\t"
                 "s_waitcnt vmcnt(0)"
                 : "=&v"(a), "=&v"(b), "=&v"(c), "=&v"(d) : "v"(p) : "memory");
}
// Single 16B coherent store: h[8] as f16 + embedded toggle bit (one packet).
__device__ __forceinline__ void store16_coh(void* p, v4u v) {
    asm volatile("global_store_dwordx4 %0, %1, off sc0 sc1"
                 :: "v"(p), "v"(v) : "memory");
}

// 6-stage DPP wave64 sum; total lands in lanes 48-63 (read lane 63).
// VALU pipe (~150-250cy for 4 interleaved chains) vs the shuffle version's
// LDS-pipe ds_bpermute chain (~400cy). Wave-local: no protocol change.
#define DPP_ADD(v, ctrl)                                                      \
    v += __int_as_float(__builtin_amdgcn_update_dpp(                          \
        0, __float_as_int(v), (ctrl), 0xf, 0xf, true))
#define RED_STAGE(ctrl) do { DPP_ADD(pr, ctrl); DPP_ADD(pz, ctrl);            \
                             DPP_ADD(pxn, ctrl); DPP_ADD(phn, ctrl); } while (0)

// Persistent GRU. 256 WGs x 512 threads (8 waves), one WG per CU.
// Wave wv owns element e = wg*8+wv.
//   x-side:  lane l covers cols 4l + 256m (m<8)  [unchanged from baseline]
//   h-side:  lane l covers cols 8l + 512m (m<4)  [b128-friendly; legal since
//            the wave-wide reduce makes per-lane column ownership free]
// Publish protocol (byte-identical to the 21.8ms baseline): WG's h[8] as f16 =
// ONE dwordx4 record; toggle(s)=((s>>1)^s)&1 in record LSB; 2 slots kill ABA;
// wave 0 polls, __syncthreads releases, tid0 publishes after sync2.
__global__ __launch_bounds__(kTHR, 2)
void gru_persistent(const float* __restrict__ x,    // [S,H] f32
                    const float* __restrict__ Wih,  // [3H,H] f32
                    const float* __restrict__ Whh,  // [3H,H] f32
                    const float* __restrict__ bih,  // [3H] f32
                    const float* __restrict__ bhh,  // [3H] f32
                    float* __restrict__ out,        // [H] f32
                    unsigned char* __restrict__ rec) // 2 slots * 4096 B (zeroed)
{
    __shared__ __align__(16) unsigned short hlds[kH];  // h_t as f16, col c at [c]
    __shared__ __align__(16) unsigned short hpub[8];

    const int wg  = blockIdx.x;
    const int tid = threadIdx.x;
    const int wv  = tid >> 6;      // 0..7
    const int l   = tid & 63;      // 0..63
    const int e   = wg * 8 + wv;
    const int cb  = 4 * l;         // x-side col base
    const int hb  = 8 * l;         // h-side col base

    // Weights: W_hh slice as f32 pairs (96 regs, 8-col blocks),
    //          W_ih as packed bf16 (24 regs, 4-col blocks).
    v2f   whh2[3][4][4];
    uint2 wihp[3][8];
#pragma unroll
    for (int G = 0; G < 3; ++G) {
        const size_t row = (size_t)(G * kH + e) * kH;
#pragma unroll
        for (int m = 0; m < 4; ++m) {
            const size_t off = row + hb + 512 * m;
            const float4 w0 = *(const float4*)(Whh + off);
            const float4 w1 = *(const float4*)(Whh + off + 4);
            whh2[G][m][0][0] = w0.x; whh2[G][m][0][1] = w0.y;
            whh2[G][m][1][0] = w0.z; whh2[G][m][1][1] = w0.w;
            whh2[G][m][2][0] = w1.x; whh2[G][m][2][1] = w1.y;
            whh2[G][m][3][0] = w1.z; whh2[G][m][3][1] = w1.w;
        }
#pragma unroll
        for (int m = 0; m < 8; ++m) {
            const float4 iw = *(const float4*)(Wih + row + cb + 256 * m);
            wihp[G][m].x = pkbf(iw.x, iw.y);
            wihp[G][m].y = pkbf(iw.z, iw.w);
        }
    }
    const float bir  = bih[e];
    const float biz  = bih[kH + e];
    const float bin_ = bih[2 * kH + e];
    const float bhr  = bhh[e];
    const float bhz  = bhh[kH + e];
    const float bhn  = bhh[2 * kH + e];

    float hold = 0.0f;  // h for element e (valid on l==63)

#pragma unroll 1
    for (int t = 0; t < kS; ++t) {
        // ---- x projection (cached loads; overlaps inter-WG skew) ----
        const float* xrow = x + (size_t)t * kH;
        v2f ar = {0.f, 0.f}, az = {0.f, 0.f}, an = {0.f, 0.f};
#pragma unroll
        for (int m = 0; m < 8; ++m) {
            const float4 xv = *(const float4*)(xrow + cb + 256 * m);
            v2f x0; x0[0] = xv.x; x0[1] = xv.y;
            v2f x1; x1[0] = xv.z; x1[1] = xv.w;
            ar += unpk_bf(wihp[0][m].x) * x0 + unpk_bf(wihp[0][m].y) * x1;
            az += unpk_bf(wihp[1][m].x) * x0 + unpk_bf(wihp[1][m].y) * x1;
            an += unpk_bf(wihp[2][m].x) * x0 + unpk_bf(wihp[2][m].y) * x1;
        }

        // ---- wave 0: poll all 256 records for step-t toggle; data = payload ----
        if (tid < 64) {
            const unsigned int tg = (unsigned int)(((t >> 1) ^ t) & 1);
            const char* base = (const char*)rec + (t & 1) * 4096 + tid * 16;
            v4u r0, r1, r2, r3;
            for (;;) {
                poll4(base, r0, r1, r2, r3);
                const int ok = ((r0.x & 1u) == tg) & ((r1.x & 1u) == tg) &
                               ((r2.x & 1u) == tg) & ((r3.x & 1u) == tg);
                if (__all(ok)) break;
            }
            // broadcast h_t to LDS: lane i writes records i, i+64, i+128, i+192
            *(v4u*)&hlds[tid * 8]         = r0;
            *(v4u*)&hlds[(tid + 64) * 8]  = r1;
            *(v4u*)&hlds[(tid + 128) * 8] = r2;
            *(v4u*)&hlds[(tid + 192) * 8] = r3;
        }
        __syncthreads();   // sync1: orders hlds broadcast vs h-proj reads

        // ---- h projection from LDS f16: 4x ds_read_b128 per lane ----
        v2f hr = {0.f, 0.f}, hz = {0.f, 0.f}, hn = {0.f, 0.f};
#pragma unroll
        for (int m = 0; m < 4; ++m) {
            const v4u hu = *(const v4u*)&hlds[hb + 512 * m];
            const v2f h0 = cvt2h(hu.x);
            const v2f h1 = cvt2h(hu.y);
            const v2f h2 = cvt2h(hu.z);
            const v2f h3 = cvt2h(hu.w);
            hr += whh2[0][m][0] * h0 + whh2[0][m][1] * h1 +
                  whh2[0][m][2] * h2 + whh2[0][m][3] * h3;
            hz += whh2[1][m][0] * h0 + whh2[1][m][1] * h1 +
                  whh2[1][m][2] * h2 + whh2[1][m][3] * h3;
            hn += whh2[2][m][0] * h0 + whh2[2][m][1] * h1 +
                  whh2[2][m][2] * h2 + whh2[2][m][3] * h3;
        }

        // ---- full-wave DPP reduce (VALU pipe); sum lands in lane 63 ----
        float pr  = ar[0] + ar[1] + hr[0] + hr[1];
        float pz  = az[0] + az[1] + hz[0] + hz[1];
        float pxn = an[0] + an[1];
        float phn = hn[0] + hn[1];
        RED_STAGE(0xB1);   // quad_perm [1,0,3,2] : xor1
        RED_STAGE(0x4E);   // quad_perm [2,3,0,1] : xor2
        RED_STAGE(0x141);  // row_half_mirror     : xor7 within 8 -> 8-group sums
        RED_STAGE(0x140);  // row_mirror          : xor15 within 16 -> row sums
        RED_STAGE(0x142);  // row_bcast15         : row1+=row0, (row2,3 unused mix)
        RED_STAGE(0x143);  // row_bcast31         : rows2,3 += lane31 -> lane63 total

        if (l == 63) {
            const float r = 1.f / (1.f + __expf(-(pr + bir + bhr)));
            const float z = 1.f / (1.f + __expf(-(pz + biz + bhz)));
            const float a = (pxn + bin_) + r * (phn + bhn);
            const float ee = __expf(-2.f * fabsf(a));
            float th = (1.f - ee) / (1.f + ee);
            th = (a < 0.f) ? -th : th;
            hold = (1.f - z) * th + z * hold;
            const __half hh = __float2half(hold);
            hpub[wv] = *(const unsigned short*)&hh;
        }
        __syncthreads();   // sync2: orders hpub writes vs tid0 pack+store

        // ---- publish: ONE 16B coherent store (data + toggle in one packet) ----
        if (tid == 0) {
            v4u p = *(const v4u*)hpub;
            const unsigned int tgw = (unsigned int)((((t + 1) >> 1) ^ (t + 1)) & 1);
            p.x = (p.x & ~1u) | tgw;
            store16_coh((char*)rec + ((t + 1) & 1) * 4096 + wg * 16, p);
        }
    }

    if (l == 63)
        out[e] = hold;
}

extern "C" void kernel_launch(void* const* d_in, const int* in_sizes, int n_in,
                              void* d_out, int out_size, void* d_ws, size_t ws_size,
                              hipStream_t stream) {
    (void)in_sizes; (void)n_in; (void)out_size; (void)ws_size;
    const float* x   = (const float*)d_in[0];
    const float* Wih = (const float*)d_in[1];
    const float* Whh = (const float*)d_in[2];
    const float* bih = (const float*)d_in[3];
    const float* bhh = (const float*)d_in[4];

    unsigned char* rec = (unsigned char*)d_ws;   // 2 slots * 4096 B
    hipMemsetAsync(rec, 0, 8192, stream);        // h_0 = 0, slot-0 toggle 0; slot-1 waits
    gru_persistent<<<dim3(kNWG), dim3(kTHR), 0, stream>>>(
        x, Wih, Whh, bih, bhh, (float*)d_out, rec);
}